// Round 16
// baseline (239.100 us; speedup 1.0000x reference)
//
#include <hip/hip_runtime.h>
#include <hip/hip_bf16.h>

typedef __hip_bfloat16 bf16;
typedef __attribute__((ext_vector_type(8))) short short8;
typedef __attribute__((ext_vector_type(4))) short short4v;
typedef __attribute__((ext_vector_type(4))) float floatx4;

#define NPIX 65536   // 256*256

__device__ __forceinline__ float b2f(bf16 v) { return __bfloat162float(v); }
__device__ __forceinline__ bf16 f2b(float v) { return __float2bfloat16(v); }
__device__ __forceinline__ short f2bs(float v) { bf16 t = __float2bfloat16(v); return *(short*)&t; }
__device__ __forceinline__ float us2f(unsigned short u) {
  union { unsigned int i; float f; } t; t.i = ((unsigned int)u) << 16; return t.f;
}
__device__ __forceinline__ float gelu_f(float v) {
  return 0.5f * v * (1.f + erff(v * 0.7071067811865476f));
}

// ---- workspace layout (bytes) ----
// Per-batch qkv region: bf16 [192, NPIX] (24 MB). Batch b at qkvb + b*192*NPIX.
//   planes 0..63 q / h1; 64..127 k; 128..191 v / opx
#define OFF_KV  50331648u     // fp32 [2,8,72,8]
#define OFF_KS  50368512u     // fp32 [2,8,72]
#define OFF_WP  50373120u     // bf16 wpack[9][64co][64ci] = 73,728 B

// pack proj_w [co][ci][p] fp32 -> wpack[p][co][ci] bf16; also zero kv/ksum.
__global__ void k_pack(const float* __restrict__ pw, bf16* __restrict__ wpack,
                       float* __restrict__ kvz) {
  int i = blockIdx.x * 256 + threadIdx.x;   // [0, 36864)
  if (i < 10368) kvz[i] = 0.f;              // kv (9216) + ksum (1152), contiguous
  int p = i >> 12, rem = i & 4095;
  int co = rem >> 6, ci = rem & 63;
  wpack[i] = f2b(pw[(co * 64 + ci) * 9 + p]);
}

// ============ shared MFMA-GEMM staging ============
__device__ __forceinline__ void stage_f32(const float* __restrict__ src, bf16* tile) {
  int tid = threadIdx.x;
  int px = tid & 127, chalf = tid >> 7;
#pragma unroll
  for (int it = 0; it < 8; ++it) {
    int ci0 = it * 8 + chalf * 4;
    short4v w;
#pragma unroll
    for (int j = 0; j < 4; ++j) w[j] = f2bs(src[((size_t)(ci0 + j) << 16) + px]);
    *(short4v*)&tile[px * 72 + ci0] = w;
  }
}

// ============ qkv 1x1 conv via MFMA, 3 sections fused: grid (512, 2b) ============
__global__ __launch_bounds__(256) void k_qkv_mfma(const float* __restrict__ x,
                                                  const float* __restrict__ qkv_w,
                                                  const float* __restrict__ qkv_b,
                                                  bf16* __restrict__ qkv) {
  __shared__ __align__(16) bf16 tile[128 * 72];
  int tid = threadIdx.x;
  int wv = tid >> 6, ln = tid & 63;
  int n0 = blockIdx.x << 7, b = blockIdx.y;
  stage_f32(x + ((size_t)b << 22) + n0, tile);

  int m = ln & 15, quad = ln >> 4;
  int co = wv * 16 + m;
  short8 afrag[3][2];
#pragma unroll
  for (int sec = 0; sec < 3; ++sec)
#pragma unroll
    for (int s = 0; s < 2; ++s) {
      short8 af;
#pragma unroll
      for (int j = 0; j < 8; ++j)
        af[j] = f2bs(qkv_w[sec * 4096 + co * 64 + s * 32 + quad * 8 + j]);
      afrag[sec][s] = af;
    }
  __syncthreads();

  floatx4 acc[3][8];
#pragma unroll
  for (int sec = 0; sec < 3; ++sec)
#pragma unroll
    for (int nt = 0; nt < 8; ++nt) acc[sec][nt] = (floatx4){0.f, 0.f, 0.f, 0.f};

#pragma unroll
  for (int s = 0; s < 2; ++s) {
    int base = m * 72 + s * 32 + quad * 8;
#pragma unroll
    for (int nt = 0; nt < 8; ++nt) {
      short8 bfrag = *(const short8*)&tile[base + nt * 16 * 72];
#pragma unroll
      for (int sec = 0; sec < 3; ++sec)
        acc[sec][nt] = __builtin_amdgcn_mfma_f32_16x16x32_bf16(afrag[sec][s], bfrag,
                                                               acc[sec][nt], 0, 0, 0);
    }
  }

  bf16* qb = qkv + ((size_t)(b * 192) << 16);
#pragma unroll
  for (int sec = 0; sec < 3; ++sec) {
    bool relu = (sec < 2);
#pragma unroll
    for (int r = 0; r < 4; ++r) {
      int co_r = wv * 16 + quad * 4 + r;
      float bias = qkv_b[sec * 64 + co_r];
      bf16* op = qb + ((size_t)(sec * 64 + co_r) << 16) + n0;
#pragma unroll
      for (int nt = 0; nt < 8; ++nt) {
        float v = acc[sec][nt][r] + bias;
        if (relu) v = fmaxf(v, 0.f);
        op[nt * 16 + m] = f2b(v);
      }
    }
  }
}

// DPP butterfly add: v += dpp_permute(v). VALU-only, no DS-pipe traffic.
template <int CTRL>
__device__ __forceinline__ float dpp_add(float v) {
  int t = __builtin_amdgcn_update_dpp(0, __builtin_bit_cast(int, v), CTRL, 0xf, 0xf, true);
  return v + __builtin_bit_cast(float, t);
}

// sum across each row of 16 lanes (result in all 16 lanes of the row)
__device__ __forceinline__ float rowsum16(float v) {
  v = dpp_add<0xB1>(v);   // quad_perm(1,0,3,2)  : xor 1
  v = dpp_add<0x4E>(v);   // quad_perm(2,3,0,1)  : xor 2
  v = dpp_add<0x141>(v);  // row_half_mirror     : xor 4
  v = dpp_add<0x140>(v);  // row_mirror          : xor 8
  return v;
}

// load one bf16 image row segment [x0-1 .. x0+8] as floats (zeros at borders)
__device__ __forceinline__ void loadrow10(const unsigned short* __restrict__ plane,
                                          int y, int x0, float kf[10]) {
  if ((unsigned)y < 256u) {
    const unsigned short* row = plane + y * 256;
    short8 k8 = *(const short8*)&row[x0];
#pragma unroll
    for (int j = 0; j < 8; ++j) kf[1 + j] = us2f((unsigned short)k8[j]);
    kf[0] = (x0 > 0) ? us2f(row[x0 - 1]) : 0.f;
    kf[9] = (x0 + 8 < 256) ? us2f(row[x0 + 8]) : 0.f;
  } else {
#pragma unroll
    for (int j = 0; j < 10; ++j) kf[j] = 0.f;
  }
}

// load bf16 row segment [x0-1 .. x0+4] as floats (zeros at borders); x0 mult of 4
__device__ __forceinline__ void loadrow6(const unsigned short* __restrict__ plane,
                                         int y, int x0, float kf[6]) {
  if ((unsigned)y < 256u) {
    const unsigned short* row = plane + y * 256;
    short4v k4 = *(const short4v*)&row[x0];
#pragma unroll
    for (int j = 0; j < 4; ++j) kf[1 + j] = us2f((unsigned short)k4[j]);
    kf[0] = (x0 > 0) ? us2f(row[x0 - 1]) : 0.f;
    kf[5] = (x0 + 4 < 256) ? us2f(row[x0 + 4]) : 0.f;
  } else {
#pragma unroll
    for (int j = 0; j < 6; ++j) kf[j] = 0.f;
  }
}

// Attention stats v7: 8 px/thread via short8 loads. grid (32, 8c, 16hz)
__global__ __launch_bounds__(256) void k_stats(const bf16* __restrict__ qkv,
                                               float* __restrict__ kv,
                                               float* __restrict__ ksum) {
  int tid = threadIdx.x;
  int chunk = blockIdx.x, c = blockIdx.y;
  int hz = blockIdx.z, h = hz & 7, b = hz >> 3;
  int r = tid >> 5, xseg = tid & 31;
  int y = (chunk << 3) + r;
  int x0 = xseg << 3;
  const bf16* qb = qkv + ((size_t)(b * 192) << 16);
  const unsigned short* kp = (const unsigned short*)qb + (((size_t)(64 + h * 8 + c)) << 16);
  const unsigned short* vp = (const unsigned short*)qb + (((size_t)(128 + h * 8)) << 16);

  // 3 k rows, halo'd
  float kf[3][10];
#pragma unroll
  for (int rr = 0; rr < 3; ++rr) loadrow10(kp, y + rr - 1, x0, kf[rr]);

  // 8 v planes, 8 px each
  short8 varr[8];
#pragma unroll
  for (int e = 0; e < 8; ++e)
    varr[e] = *(const short8*)&vp[((size_t)e << 16) + y * 256 + x0];

  __shared__ float red[16][81];
  int r16 = tid >> 4;
  bool wr = (tid & 15) == 0;

  // ksum: 9 taps
#pragma unroll
  for (int rr = 0; rr < 3; ++rr)
#pragma unroll
    for (int t = 0; t < 3; ++t) {
      float s = 0.f;
#pragma unroll
      for (int i = 0; i < 8; ++i) s += kf[rr][i + t];
      s = rowsum16(s);
      if (wr) red[r16][72 + rr * 3 + t] = s;
    }

  // kv: 9 taps x 8 v-channels
#pragma unroll
  for (int e = 0; e < 8; ++e) {
    float vf[8];
#pragma unroll
    for (int i = 0; i < 8; ++i) vf[i] = us2f((unsigned short)varr[e][i]);
#pragma unroll
    for (int rr = 0; rr < 3; ++rr)
#pragma unroll
      for (int t = 0; t < 3; ++t) {
        float s = 0.f;
#pragma unroll
        for (int i = 0; i < 8; ++i) s = fmaf(kf[rr][i + t], vf[i], s);
        s = rowsum16(s);
        if (wr) red[r16][(rr * 3 + t) * 8 + e] = s;
      }
  }
  __syncthreads();
  if (tid < 81) {
    float s = 0.f;
#pragma unroll
    for (int j = 0; j < 16; ++j) s += red[j][tid];
    int dbase = (b * 8 + h) * 72 + c * 9;
    if (tid < 72) atomicAdd(&kv[((dbase + (tid >> 3)) << 3) + (tid & 7)], s);
    else atomicAdd(&ksum[dbase + (tid - 72)], s);
  }
}

// k_apply v3: 4 px/thread, kv/ksum in LDS, c-loop ROLLED. grid (64, 8h, 2b)
__global__ __launch_bounds__(256) void k_apply(bf16* __restrict__ qkv,
                                               const float* __restrict__ kv,
                                               const float* __restrict__ ksum) {
  int tid = threadIdx.x;
  int chunk = blockIdx.x, h = blockIdx.y, b = blockIdx.z;
  const float* kvb = kv + (size_t)((b * 8 + h) * 72) * 8;
  const float* ksb = ksum + (b * 8 + h) * 72;
  bf16* qb = qkv + ((size_t)(b * 192) << 16);
  bf16* opx = qb + ((size_t)128 << 16);

  __shared__ float skv[576];
  __shared__ float sks[72];
  for (int i = tid; i < 648; i += 256) {
    if (i < 576) skv[i] = kvb[i];
    else sks[i - 576] = ksb[i - 576];
  }
  __syncthreads();

  int r = tid >> 6, xseg = tid & 63;
  int y = (chunk << 2) + r;
  int x0 = xseg << 2;

  float num[8][4], den[4];
#pragma unroll
  for (int i = 0; i < 4; ++i) {
    den[i] = 0.f;
#pragma unroll
    for (int e = 0; e < 8; ++e) num[e][i] = 0.f;
  }

#pragma unroll 1
  for (int c = 0; c < 8; ++c) {
    const unsigned short* qp = (const unsigned short*)qb + ((size_t)(h * 8 + c) << 16);
    float kf[3][6];
#pragma unroll
    for (int rr = 0; rr < 3; ++rr) loadrow6(qp, y + rr - 1, x0, kf[rr]);
#pragma unroll
    for (int rr = 0; rr < 3; ++rr)
#pragma unroll
      for (int t = 0; t < 3; ++t) {
        int d = c * 9 + rr * 3 + t;
        float ksv = sks[d];
#pragma unroll
        for (int i = 0; i < 4; ++i) den[i] = fmaf(kf[rr][i + t], ksv, den[i]);
#pragma unroll
        for (int e = 0; e < 8; ++e) {
          float kvv = skv[d * 8 + e];
#pragma unroll
          for (int i = 0; i < 4; ++i) num[e][i] = fmaf(kf[rr][i + t], kvv, num[e][i]);
        }
      }
  }

#pragma unroll
  for (int i = 0; i < 4; ++i) {
    float inv = 1.f / (den[i] + 1e-6f);
    int n = y * 256 + x0 + i;
    short8 ov;
#pragma unroll
    for (int e = 0; e < 8; ++e) ov[e] = f2bs(num[e][i] * inv);
    *(short8*)&opx[((size_t)n << 6) + h * 8] = ov;
  }
}

// proj 3x3 conv + residual + FUSED ffn1, v8: v7 DMA staging + XCD-aware
// block swizzle (T1). y-adjacent blocks share 2/3 staged opx rows; default
// dispatch round-robins them across 8 non-coherent XCD L2s -> staging misses
// at ~900cy. Swizzle gives each XCD a contiguous 64-row band (working set
// ~2.1 MB < 4 MB L2) so re-reads hit a sibling's L2 line (~200cy). nwg=2048,
// nwg%8==0 -> simple bijective remap. grid (4, 256, 2b); 25.3 KB LDS.
__global__ __launch_bounds__(256) void k_proj_ffn1(bf16* qkv,
                                                   const bf16* __restrict__ wpack,
                                                   const float* __restrict__ proj_b,
                                                   const float* __restrict__ x,
                                                   const float* __restrict__ w1,
                                                   const float* __restrict__ b1,
                                                   float* __restrict__ out) {
  __shared__ __align__(16) bf16 tile[3 * 66 * 64];   // [dyr][px][ci], swizzled; 25.3 KB
  int tid = threadIdx.x;
  int wv = tid >> 6, ln = tid & 63;
  // XCD swizzle: flat d (bx fastest) -> g = (d%8)*256 + d/8; XCD k owns a
  // contiguous 256-block chunk = one batch x 64-row band x all quarters.
  int d = blockIdx.x + (blockIdx.y << 2) + (blockIdx.z << 10);   // [0,2048)
  int g = ((d & 7) << 8) + (d >> 3);
  int b = g >> 10;
  int rem = g & 1023;
  int y = rem >> 2;
  int quarter = rem & 3;
  const bf16* opx = qkv + ((size_t)(b * 192 + 128) << 16);
  int x0 = quarter << 6;
  int m = ln & 15, quad = ln >> 4;
  int co = wv * 16 + m;
  int co0 = wv * 16 + quad * 4;

  // preload ALL 18 A-fragments first: 18 independent L2 loads in flight.
  short8 afrag[18];
#pragma unroll
  for (int s = 0; s < 18; ++s) {
    int p = s >> 1;
    int ci0 = (s & 1) * 32 + quad * 8;
    afrag[s] = *(const short8*)&wpack[(p * 64 + co) * 64 + ci0];
  }

  // DMA-stage the aligned body: LDS dest LINEAR, global src pre-swizzled.
#pragma unroll
  for (int it = 0; it < 6; ++it) {
    int dd = it * 256 + tid;
    int dyr = dd >> 9, r = dd & 511;
    int px = 1 + (r >> 3), sub = r & 7;
    int slot = dyr * 66 + px;
    int gy = y + dyr - 1;
    gy = (gy < 0) ? 0 : ((gy > 255) ? 255 : gy);
    int gx = x0 + px - 1;                         // always in [0,255]
    int gsub = sub ^ (px & 7);
    const bf16* src = &opx[(((size_t)(gy << 8) + gx) << 6) + (gsub << 3)];
    __builtin_amdgcn_global_load_lds((const void*)src,
                                     (void*)&tile[(slot << 6) + (sub << 3)],
                                     16, 0, 0);
  }

  // halo columns px=0 and px=65: 48 granules via predicated regular loads.
  if (tid < 48) {
    int colsel = tid >= 24;
    int t = tid - colsel * 24;
    int dyr = t >> 3, sub = t & 7;
    int px = colsel ? 65 : 0;
    int gx = x0 + px - 1;
    int gy = y + dyr - 1;
    short8 val = {0, 0, 0, 0, 0, 0, 0, 0};
    if ((unsigned)gy < 256u && (unsigned)gx < 256u)
      val = *(const short8*)&opx[(((size_t)(gy << 8) + gx) << 6) + ((sub ^ (px & 7)) << 3)];
    int slot = dyr * 66 + px;
    *(short8*)&tile[(slot << 6) + (sub << 3)] = val;
  }

  // EARLY x prefetch: independent of tile; in flight across proj phase.
  float xv[4][4];
#pragma unroll
  for (int nt = 0; nt < 4; ++nt) {
    int gx = x0 + nt * 16 + m;
#pragma unroll
    for (int r = 0; r < 4; ++r)
      xv[nt][r] = x[((size_t)(b * 64 + co0 + r) << 16) + (y << 8) + gx];
  }
  __syncthreads();   // drains vmcnt: DMAs + halo writes landed

  // edge blocks only (16 of 2048): zero the clamped OOB row.
  if (y == 0 || y == 255) {
    int dyrz = (y == 0) ? 0 : 2;
    short8 z8 = {0, 0, 0, 0, 0, 0, 0, 0};
    for (int q2 = tid; q2 < 528; q2 += 256) {
      int slot = dyrz * 66 + (q2 >> 3);
      *(short8*)&tile[(slot << 6) + ((q2 & 7) << 3)] = z8;
    }
    __syncthreads();
  }

  floatx4 acc[4];
#pragma unroll
  for (int nt = 0; nt < 4; ++nt) acc[nt] = (floatx4){0.f, 0.f, 0.f, 0.f};

#pragma unroll
  for (int s = 0; s < 18; ++s) {
    int p = s >> 1;
    int dyr = p / 3, dx = p % 3;
    int ci0 = (s & 1) * 32 + quad * 8;
    int slot0 = dyr * 66;
#pragma unroll
    for (int nt = 0; nt < 4; ++nt) {
      int px = nt * 16 + m + dx;           // tile px index (gx = x0 + px - 1)
      int ci = ci0 ^ ((px & 7) << 3);
      short8 bfrag = *(const short8*)&tile[((slot0 + px) << 6) + ci];
      acc[nt] = __builtin_amdgcn_mfma_f32_16x16x32_bf16(afrag[s], bfrag, acc[nt], 0, 0, 0);
    }
  }

  float bias4[4];
#pragma unroll
  for (int r = 0; r < 4; ++r) bias4[r] = proj_b[co0 + r];

  __syncthreads();   // all tile reads done; safe to reuse LDS for the out-tile

  // epilogue: out = xv + bias + acc (fp32 store) + bf16 stash to LDS [64px][64ci]
#pragma unroll
  for (int nt = 0; nt < 4; ++nt) {
    int px = nt * 16 + m;
    int gx = x0 + px;
    short4v v4;
#pragma unroll
    for (int r = 0; r < 4; ++r) {
      int co_r = co0 + r;
      size_t idx = ((size_t)(b * 64 + co_r) << 16) + (y << 8) + gx;
      float ov = xv[nt][r] + bias4[r] + acc[nt][r];
      out[idx] = ov;
      v4[r] = f2bs(ov);
    }
    int t2i = px * 64 + (((co0 >> 3) ^ (px & 7)) << 3) + (co0 & 7);
    *(short4v*)&tile[t2i] = v4;
  }
  __syncthreads();

  // ffn1: h1 = gelu(w1 . out + b1) for these 64 px -> q planes (0..63)
  short8 af1[2];
#pragma unroll
  for (int s = 0; s < 2; ++s) {
    short8 af;
#pragma unroll
    for (int j = 0; j < 8; ++j) af[j] = f2bs(w1[co * 64 + s * 32 + quad * 8 + j]);
    af1[s] = af;
  }
  floatx4 acc1[4];
#pragma unroll
  for (int nt = 0; nt < 4; ++nt) acc1[nt] = (floatx4){0.f, 0.f, 0.f, 0.f};
#pragma unroll
  for (int s = 0; s < 2; ++s) {
    int ci0 = s * 32 + quad * 8;
#pragma unroll
    for (int nt = 0; nt < 4; ++nt) {
      int px = nt * 16 + m;
      int ci = ci0 ^ ((px & 7) << 3);
      short8 bfrag = *(const short8*)&tile[px * 64 + ci];
      acc1[nt] = __builtin_amdgcn_mfma_f32_16x16x32_bf16(af1[s], bfrag, acc1[nt], 0, 0, 0);
    }
  }
  bf16* qb = qkv + ((size_t)(b * 192) << 16);
#pragma unroll
  for (int r = 0; r < 4; ++r) {
    int co_r = co0 + r;
    float bias = b1[co_r];
    bf16* op = qb + ((size_t)co_r << 16) + (y << 8) + x0;
#pragma unroll
    for (int nt = 0; nt < 4; ++nt)
      op[nt * 16 + m] = f2b(gelu_f(acc1[nt][r] + bias));
  }
}

// FUSED depthwise 3x3 + GELU + ffn2 1x1 + residual, + XCD swizzle (same
// mechanism: y-adjacent blocks share 2/3 h1 rows). nwg=1024, %8==0.
// grid (512, 1, 2b).
__global__ __launch_bounds__(256) void k_dwffn2(const bf16* __restrict__ qkv,
                                                const float* __restrict__ dw_w,
                                                const float* __restrict__ dw_b,
                                                const float* __restrict__ w2,
                                                const float* __restrict__ b2,
                                                float* __restrict__ out) {
  __shared__ __align__(16) bf16 tile[128 * 64];      // [px][ci], swizzled; 16 KB
  int tid = threadIdx.x;
  // XCD swizzle: flat d -> g = (d%8)*128 + d/8; XCD k owns 128 contiguous
  // blocks = one batch x 64-row band x both halves.
  int d = blockIdx.x + (blockIdx.z << 9);            // [0,1024)
  int g = ((d & 7) << 7) + (d >> 3);
  int b = g >> 9;
  int rem = g & 511;
  int y = rem >> 1, half = rem & 1;
  int x0 = half << 7;
  const bf16* qb = qkv + ((size_t)(b * 192) << 16);

  // ---- dw phase: 4 units/thread; unit = (ci, xseg of 8 px) ----
#pragma unroll 1
  for (int u = 0; u < 4; ++u) {
    int id = u * 256 + tid;                // [0, 1024)
    int ci = id >> 4, xseg = id & 15;
    int gx0 = x0 + (xseg << 3);
    const unsigned short* ip = (const unsigned short*)qb + ((size_t)ci << 16);

    float w[9];
#pragma unroll
    for (int p = 0; p < 9; ++p) w[p] = dw_w[ci * 9 + p];
    float bias = dw_b[ci];

    float kf[3][10];
#pragma unroll
    for (int rr = 0; rr < 3; ++rr) loadrow10(ip, y + rr - 1, gx0, kf[rr]);

#pragma unroll
    for (int i = 0; i < 8; ++i) {
      float acc = bias;
#pragma unroll
      for (int rr = 0; rr < 3; ++rr)
#pragma unroll
        for (int t = 0; t < 3; ++t)
          acc = fmaf(kf[rr][i + t], w[rr * 3 + t], acc);
      int px = (xseg << 3) + i;            // local px in [0,128)
      int addr = (px << 6) + ((((ci >> 3) ^ (px & 7)) << 3) | (ci & 7));
      tile[addr] = f2b(gelu_f(acc));
    }
  }
  __syncthreads();

  // ---- ffn2 GEMM from LDS + residual RMW ----
  int wv = tid >> 6, ln = tid & 63;
  int m = ln & 15, quad = ln >> 4;
  int co = wv * 16 + m;
  short8 afrag[2];
#pragma unroll
  for (int s = 0; s < 2; ++s) {
    short8 af;
#pragma unroll
    for (int j = 0; j < 8; ++j) af[j] = f2bs(w2[co * 64 + s * 32 + quad * 8 + j]);
    afrag[s] = af;
  }

  floatx4 acc[8];
#pragma unroll
  for (int nt = 0; nt < 8; ++nt) acc[nt] = (floatx4){0.f, 0.f, 0.f, 0.f};
#pragma unroll
  for (int s = 0; s < 2; ++s) {
    int ci0 = s * 32 + quad * 8;
#pragma unroll
    for (int nt = 0; nt < 8; ++nt) {
      int px = nt * 16 + m;
      int ci = ci0 ^ ((px & 7) << 3);
      short8 bfrag = *(const short8*)&tile[(px << 6) + ci];
      acc[nt] = __builtin_amdgcn_mfma_f32_16x16x32_bf16(afrag[s], bfrag, acc[nt], 0, 0, 0);
    }
  }

#pragma unroll
  for (int r = 0; r < 4; ++r) {
    int co_r = wv * 16 + quad * 4 + r;
    float bias = b2[co_r];
    float* op = out + ((size_t)b << 22) + ((size_t)co_r << 16) + (y << 8) + x0;
#pragma unroll
    for (int nt = 0; nt < 8; ++nt) {
      int i = nt * 16 + m;
      op[i] = op[i] + bias + acc[nt][r];
    }
  }
}

extern "C" void kernel_launch(void* const* d_in, const int* in_sizes, int n_in,
                              void* d_out, int out_size, void* d_ws, size_t ws_size,
                              hipStream_t stream) {
  const float* x      = (const float*)d_in[0];
  const float* qkv_w  = (const float*)d_in[1];
  const float* qkv_b  = (const float*)d_in[2];
  const float* proj_w = (const float*)d_in[3];
  const float* proj_b = (const float*)d_in[4];
  const float* ffn1_w = (const float*)d_in[5];
  const float* ffn1_b = (const float*)d_in[6];
  const float* dw_w   = (const float*)d_in[7];
  const float* dw_b   = (const float*)d_in[8];
  const float* ffn2_w = (const float*)d_in[9];
  const float* ffn2_b = (const float*)d_in[10];
  float* out = (float*)d_out;

  char* ws = (char*)d_ws;
  bf16*  qkvb  = (bf16*)ws;                    // 2 batch regions of [192, NPIX]
  float* kvb   = (float*)(ws + OFF_KV);
  float* ksb   = (float*)(ws + OFF_KS);
  bf16*  wpack = (bf16*)(ws + OFF_WP);

  // 6 launches total
  k_pack<<<144, 256, 0, stream>>>(proj_w, wpack, kvb);
  k_qkv_mfma<<<dim3(512, 2), 256, 0, stream>>>(x, qkv_w, qkv_b, qkvb);
  k_stats<<<dim3(32, 8, 16), 256, 0, stream>>>(qkvb, kvb, ksb);
  k_apply<<<dim3(64, 8, 2), 256, 0, stream>>>(qkvb, kvb, ksb);
  k_proj_ffn1<<<dim3(4, 256, 2), 256, 0, stream>>>(qkvb, wpack, proj_b, x,
                                                   ffn1_w, ffn1_b, out);
  k_dwffn2<<<dim3(512, 1, 2), 256, 0, stream>>>(qkvb, dw_w, dw_b,
                                                ffn2_w, ffn2_b, out);
}

// Round 17
// 235.971 us; speedup vs baseline: 1.0133x; 1.0133x over previous
//
#include <hip/hip_runtime.h>
#include <hip/hip_bf16.h>

typedef __hip_bfloat16 bf16;
typedef __attribute__((ext_vector_type(8))) short short8;
typedef __attribute__((ext_vector_type(4))) short short4v;
typedef __attribute__((ext_vector_type(4))) float floatx4;

#define NPIX 65536   // 256*256

__device__ __forceinline__ float b2f(bf16 v) { return __bfloat162float(v); }
__device__ __forceinline__ bf16 f2b(float v) { return __float2bfloat16(v); }
__device__ __forceinline__ short f2bs(float v) { bf16 t = __float2bfloat16(v); return *(short*)&t; }
__device__ __forceinline__ float us2f(unsigned short u) {
  union { unsigned int i; float f; } t; t.i = ((unsigned int)u) << 16; return t.f;
}
__device__ __forceinline__ float gelu_f(float v) {
  return 0.5f * v * (1.f + erff(v * 0.7071067811865476f));
}

// ---- workspace layout (bytes) ----
// Per-batch qkv region: bf16 [192, NPIX] (24 MB). Batch b at qkvb + b*192*NPIX.
//   planes 0..63 q / h1; 64..127 k; 128..191 v / opx
#define OFF_KV  50331648u     // fp32 [2,8,72,8]
#define OFF_KS  50368512u     // fp32 [2,8,72]
#define OFF_WP  50373120u     // bf16 wpack[9][64co][64ci] = 73,728 B

// pack proj_w [co][ci][p] fp32 -> wpack[p][co][ci] bf16; also zero kv/ksum.
__global__ void k_pack(const float* __restrict__ pw, bf16* __restrict__ wpack,
                       float* __restrict__ kvz) {
  int i = blockIdx.x * 256 + threadIdx.x;   // [0, 36864)
  if (i < 10368) kvz[i] = 0.f;              // kv (9216) + ksum (1152), contiguous
  int p = i >> 12, rem = i & 4095;
  int co = rem >> 6, ci = rem & 63;
  wpack[i] = f2b(pw[(co * 64 + ci) * 9 + p]);
}

// ============ shared MFMA-GEMM staging ============
__device__ __forceinline__ void stage_f32(const float* __restrict__ src, bf16* tile) {
  int tid = threadIdx.x;
  int px = tid & 127, chalf = tid >> 7;
#pragma unroll
  for (int it = 0; it < 8; ++it) {
    int ci0 = it * 8 + chalf * 4;
    short4v w;
#pragma unroll
    for (int j = 0; j < 4; ++j) w[j] = f2bs(src[((size_t)(ci0 + j) << 16) + px]);
    *(short4v*)&tile[px * 72 + ci0] = w;
  }
}

// ============ qkv 1x1 conv via MFMA, 3 sections fused: grid (512, 2b) ============
__global__ __launch_bounds__(256) void k_qkv_mfma(const float* __restrict__ x,
                                                  const float* __restrict__ qkv_w,
                                                  const float* __restrict__ qkv_b,
                                                  bf16* __restrict__ qkv) {
  __shared__ __align__(16) bf16 tile[128 * 72];
  int tid = threadIdx.x;
  int wv = tid >> 6, ln = tid & 63;
  int n0 = blockIdx.x << 7, b = blockIdx.y;
  stage_f32(x + ((size_t)b << 22) + n0, tile);

  int m = ln & 15, quad = ln >> 4;
  int co = wv * 16 + m;
  short8 afrag[3][2];
#pragma unroll
  for (int sec = 0; sec < 3; ++sec)
#pragma unroll
    for (int s = 0; s < 2; ++s) {
      short8 af;
#pragma unroll
      for (int j = 0; j < 8; ++j)
        af[j] = f2bs(qkv_w[sec * 4096 + co * 64 + s * 32 + quad * 8 + j]);
      afrag[sec][s] = af;
    }
  __syncthreads();

  floatx4 acc[3][8];
#pragma unroll
  for (int sec = 0; sec < 3; ++sec)
#pragma unroll
    for (int nt = 0; nt < 8; ++nt) acc[sec][nt] = (floatx4){0.f, 0.f, 0.f, 0.f};

#pragma unroll
  for (int s = 0; s < 2; ++s) {
    int base = m * 72 + s * 32 + quad * 8;
#pragma unroll
    for (int nt = 0; nt < 8; ++nt) {
      short8 bfrag = *(const short8*)&tile[base + nt * 16 * 72];
#pragma unroll
      for (int sec = 0; sec < 3; ++sec)
        acc[sec][nt] = __builtin_amdgcn_mfma_f32_16x16x32_bf16(afrag[sec][s], bfrag,
                                                               acc[sec][nt], 0, 0, 0);
    }
  }

  bf16* qb = qkv + ((size_t)(b * 192) << 16);
#pragma unroll
  for (int sec = 0; sec < 3; ++sec) {
    bool relu = (sec < 2);
#pragma unroll
    for (int r = 0; r < 4; ++r) {
      int co_r = wv * 16 + quad * 4 + r;
      float bias = qkv_b[sec * 64 + co_r];
      bf16* op = qb + ((size_t)(sec * 64 + co_r) << 16) + n0;
#pragma unroll
      for (int nt = 0; nt < 8; ++nt) {
        float v = acc[sec][nt][r] + bias;
        if (relu) v = fmaxf(v, 0.f);
        op[nt * 16 + m] = f2b(v);
      }
    }
  }
}

// DPP butterfly add: v += dpp_permute(v). VALU-only, no DS-pipe traffic.
template <int CTRL>
__device__ __forceinline__ float dpp_add(float v) {
  int t = __builtin_amdgcn_update_dpp(0, __builtin_bit_cast(int, v), CTRL, 0xf, 0xf, true);
  return v + __builtin_bit_cast(float, t);
}

// sum across each row of 16 lanes (result in all 16 lanes of the row)
__device__ __forceinline__ float rowsum16(float v) {
  v = dpp_add<0xB1>(v);   // quad_perm(1,0,3,2)  : xor 1
  v = dpp_add<0x4E>(v);   // quad_perm(2,3,0,1)  : xor 2
  v = dpp_add<0x141>(v);  // row_half_mirror     : xor 4
  v = dpp_add<0x140>(v);  // row_mirror          : xor 8
  return v;
}

// load one bf16 image row segment [x0-1 .. x0+8] as floats (zeros at borders)
__device__ __forceinline__ void loadrow10(const unsigned short* __restrict__ plane,
                                          int y, int x0, float kf[10]) {
  if ((unsigned)y < 256u) {
    const unsigned short* row = plane + y * 256;
    short8 k8 = *(const short8*)&row[x0];
#pragma unroll
    for (int j = 0; j < 8; ++j) kf[1 + j] = us2f((unsigned short)k8[j]);
    kf[0] = (x0 > 0) ? us2f(row[x0 - 1]) : 0.f;
    kf[9] = (x0 + 8 < 256) ? us2f(row[x0 + 8]) : 0.f;
  } else {
#pragma unroll
    for (int j = 0; j < 10; ++j) kf[j] = 0.f;
  }
}

// load bf16 row segment [x0-1 .. x0+4] as floats (zeros at borders); x0 mult of 4
__device__ __forceinline__ void loadrow6(const unsigned short* __restrict__ plane,
                                         int y, int x0, float kf[6]) {
  if ((unsigned)y < 256u) {
    const unsigned short* row = plane + y * 256;
    short4v k4 = *(const short4v*)&row[x0];
#pragma unroll
    for (int j = 0; j < 4; ++j) kf[1 + j] = us2f((unsigned short)k4[j]);
    kf[0] = (x0 > 0) ? us2f(row[x0 - 1]) : 0.f;
    kf[5] = (x0 + 4 < 256) ? us2f(row[x0 + 4]) : 0.f;
  } else {
#pragma unroll
    for (int j = 0; j < 6; ++j) kf[j] = 0.f;
  }
}

// Attention stats v7: 8 px/thread via short8 loads. grid (32, 8c, 16hz)
__global__ __launch_bounds__(256) void k_stats(const bf16* __restrict__ qkv,
                                               float* __restrict__ kv,
                                               float* __restrict__ ksum) {
  int tid = threadIdx.x;
  int chunk = blockIdx.x, c = blockIdx.y;
  int hz = blockIdx.z, h = hz & 7, b = hz >> 3;
  int r = tid >> 5, xseg = tid & 31;
  int y = (chunk << 3) + r;
  int x0 = xseg << 3;
  const bf16* qb = qkv + ((size_t)(b * 192) << 16);
  const unsigned short* kp = (const unsigned short*)qb + (((size_t)(64 + h * 8 + c)) << 16);
  const unsigned short* vp = (const unsigned short*)qb + (((size_t)(128 + h * 8)) << 16);

  // 3 k rows, halo'd
  float kf[3][10];
#pragma unroll
  for (int rr = 0; rr < 3; ++rr) loadrow10(kp, y + rr - 1, x0, kf[rr]);

  // 8 v planes, 8 px each
  short8 varr[8];
#pragma unroll
  for (int e = 0; e < 8; ++e)
    varr[e] = *(const short8*)&vp[((size_t)e << 16) + y * 256 + x0];

  __shared__ float red[16][81];
  int r16 = tid >> 4;
  bool wr = (tid & 15) == 0;

  // ksum: 9 taps
#pragma unroll
  for (int rr = 0; rr < 3; ++rr)
#pragma unroll
    for (int t = 0; t < 3; ++t) {
      float s = 0.f;
#pragma unroll
      for (int i = 0; i < 8; ++i) s += kf[rr][i + t];
      s = rowsum16(s);
      if (wr) red[r16][72 + rr * 3 + t] = s;
    }

  // kv: 9 taps x 8 v-channels
#pragma unroll
  for (int e = 0; e < 8; ++e) {
    float vf[8];
#pragma unroll
    for (int i = 0; i < 8; ++i) vf[i] = us2f((unsigned short)varr[e][i]);
#pragma unroll
    for (int rr = 0; rr < 3; ++rr)
#pragma unroll
      for (int t = 0; t < 3; ++t) {
        float s = 0.f;
#pragma unroll
        for (int i = 0; i < 8; ++i) s = fmaf(kf[rr][i + t], vf[i], s);
        s = rowsum16(s);
        if (wr) red[r16][(rr * 3 + t) * 8 + e] = s;
      }
  }
  __syncthreads();
  if (tid < 81) {
    float s = 0.f;
#pragma unroll
    for (int j = 0; j < 16; ++j) s += red[j][tid];
    int dbase = (b * 8 + h) * 72 + c * 9;
    if (tid < 72) atomicAdd(&kv[((dbase + (tid >> 3)) << 3) + (tid & 7)], s);
    else atomicAdd(&ksum[dbase + (tid - 72)], s);
  }
}

// k_apply v3: 4 px/thread, kv/ksum in LDS, c-loop ROLLED. grid (64, 8h, 2b)
__global__ __launch_bounds__(256) void k_apply(bf16* __restrict__ qkv,
                                               const float* __restrict__ kv,
                                               const float* __restrict__ ksum) {
  int tid = threadIdx.x;
  int chunk = blockIdx.x, h = blockIdx.y, b = blockIdx.z;
  const float* kvb = kv + (size_t)((b * 8 + h) * 72) * 8;
  const float* ksb = ksum + (b * 8 + h) * 72;
  bf16* qb = qkv + ((size_t)(b * 192) << 16);
  bf16* opx = qb + ((size_t)128 << 16);

  __shared__ float skv[576];
  __shared__ float sks[72];
  for (int i = tid; i < 648; i += 256) {
    if (i < 576) skv[i] = kvb[i];
    else sks[i - 576] = ksb[i - 576];
  }
  __syncthreads();

  int r = tid >> 6, xseg = tid & 63;
  int y = (chunk << 2) + r;
  int x0 = xseg << 2;

  float num[8][4], den[4];
#pragma unroll
  for (int i = 0; i < 4; ++i) {
    den[i] = 0.f;
#pragma unroll
    for (int e = 0; e < 8; ++e) num[e][i] = 0.f;
  }

#pragma unroll 1
  for (int c = 0; c < 8; ++c) {
    const unsigned short* qp = (const unsigned short*)qb + ((size_t)(h * 8 + c) << 16);
    float kf[3][6];
#pragma unroll
    for (int rr = 0; rr < 3; ++rr) loadrow6(qp, y + rr - 1, x0, kf[rr]);
#pragma unroll
    for (int rr = 0; rr < 3; ++rr)
#pragma unroll
      for (int t = 0; t < 3; ++t) {
        int d = c * 9 + rr * 3 + t;
        float ksv = sks[d];
#pragma unroll
        for (int i = 0; i < 4; ++i) den[i] = fmaf(kf[rr][i + t], ksv, den[i]);
#pragma unroll
        for (int e = 0; e < 8; ++e) {
          float kvv = skv[d * 8 + e];
#pragma unroll
          for (int i = 0; i < 4; ++i) num[e][i] = fmaf(kf[rr][i + t], kvv, num[e][i]);
        }
      }
  }

#pragma unroll
  for (int i = 0; i < 4; ++i) {
    float inv = 1.f / (den[i] + 1e-6f);
    int n = y * 256 + x0 + i;
    short8 ov;
#pragma unroll
    for (int e = 0; e < 8; ++e) ov[e] = f2bs(num[e][i] * inv);
    *(short8*)&opx[((size_t)n << 6) + h * 8] = ov;
  }
}

// proj 3x3 conv + residual + FUSED ffn1, v7 (round-15 best, 236.2 us total).
// Round-16 A/B: XCD swizzle cut FETCH 34->25 MB but timing neutral-negative
// -> kernel is phase-latency bound, not traffic-bound; swizzle reverted.
// grid (4, 256, 2b); 25.3 KB LDS.
__global__ __launch_bounds__(256) void k_proj_ffn1(bf16* qkv,
                                                   const bf16* __restrict__ wpack,
                                                   const float* __restrict__ proj_b,
                                                   const float* __restrict__ x,
                                                   const float* __restrict__ w1,
                                                   const float* __restrict__ b1,
                                                   float* __restrict__ out) {
  __shared__ __align__(16) bf16 tile[3 * 66 * 64];   // [dyr][px][ci], swizzled; 25.3 KB
  int tid = threadIdx.x;
  int wv = tid >> 6, ln = tid & 63;
  int quarter = blockIdx.x, y = blockIdx.y, b = blockIdx.z;
  const bf16* opx = qkv + ((size_t)(b * 192 + 128) << 16);
  int x0 = quarter << 6;
  int m = ln & 15, quad = ln >> 4;
  int co = wv * 16 + m;
  int co0 = wv * 16 + quad * 4;

  // preload ALL 18 A-fragments first: 18 independent L2 loads in flight.
  short8 afrag[18];
#pragma unroll
  for (int s = 0; s < 18; ++s) {
    int p = s >> 1;
    int ci0 = (s & 1) * 32 + quad * 8;
    afrag[s] = *(const short8*)&wpack[(p * 64 + co) * 64 + ci0];
  }

  // DMA-stage the aligned body: LDS dest LINEAR, global src pre-swizzled.
#pragma unroll
  for (int it = 0; it < 6; ++it) {
    int d = it * 256 + tid;
    int dyr = d >> 9, r = d & 511;
    int px = 1 + (r >> 3), sub = r & 7;
    int slot = dyr * 66 + px;
    int gy = y + dyr - 1;
    gy = (gy < 0) ? 0 : ((gy > 255) ? 255 : gy);
    int gx = x0 + px - 1;                         // always in [0,255]
    int gsub = sub ^ (px & 7);
    const bf16* src = &opx[(((size_t)(gy << 8) + gx) << 6) + (gsub << 3)];
    __builtin_amdgcn_global_load_lds((const void*)src,
                                     (void*)&tile[(slot << 6) + (sub << 3)],
                                     16, 0, 0);
  }

  // halo columns px=0 and px=65: 48 granules via predicated regular loads.
  if (tid < 48) {
    int colsel = tid >= 24;
    int t = tid - colsel * 24;
    int dyr = t >> 3, sub = t & 7;
    int px = colsel ? 65 : 0;
    int gx = x0 + px - 1;
    int gy = y + dyr - 1;
    short8 val = {0, 0, 0, 0, 0, 0, 0, 0};
    if ((unsigned)gy < 256u && (unsigned)gx < 256u)
      val = *(const short8*)&opx[(((size_t)(gy << 8) + gx) << 6) + ((sub ^ (px & 7)) << 3)];
    int slot = dyr * 66 + px;
    *(short8*)&tile[(slot << 6) + (sub << 3)] = val;
  }

  // EARLY x prefetch: independent of tile; in flight across proj phase.
  float xv[4][4];
#pragma unroll
  for (int nt = 0; nt < 4; ++nt) {
    int gx = x0 + nt * 16 + m;
#pragma unroll
    for (int r = 0; r < 4; ++r)
      xv[nt][r] = x[((size_t)(b * 64 + co0 + r) << 16) + (y << 8) + gx];
  }
  __syncthreads();   // drains vmcnt: DMAs + halo writes landed

  // edge blocks only (16 of 2048): zero the clamped OOB row.
  if (y == 0 || y == 255) {
    int dyrz = (y == 0) ? 0 : 2;
    short8 z8 = {0, 0, 0, 0, 0, 0, 0, 0};
    for (int q2 = tid; q2 < 528; q2 += 256) {
      int slot = dyrz * 66 + (q2 >> 3);
      *(short8*)&tile[(slot << 6) + ((q2 & 7) << 3)] = z8;
    }
    __syncthreads();
  }

  floatx4 acc[4];
#pragma unroll
  for (int nt = 0; nt < 4; ++nt) acc[nt] = (floatx4){0.f, 0.f, 0.f, 0.f};

#pragma unroll
  for (int s = 0; s < 18; ++s) {
    int p = s >> 1;
    int dyr = p / 3, dx = p % 3;
    int ci0 = (s & 1) * 32 + quad * 8;
    int slot0 = dyr * 66;
#pragma unroll
    for (int nt = 0; nt < 4; ++nt) {
      int px = nt * 16 + m + dx;           // tile px index (gx = x0 + px - 1)
      int ci = ci0 ^ ((px & 7) << 3);
      short8 bfrag = *(const short8*)&tile[((slot0 + px) << 6) + ci];
      acc[nt] = __builtin_amdgcn_mfma_f32_16x16x32_bf16(afrag[s], bfrag, acc[nt], 0, 0, 0);
    }
  }

  float bias4[4];
#pragma unroll
  for (int r = 0; r < 4; ++r) bias4[r] = proj_b[co0 + r];

  __syncthreads();   // all tile reads done; safe to reuse LDS for the out-tile

  // epilogue: out = xv + bias + acc (fp32 store) + bf16 stash to LDS [64px][64ci]
#pragma unroll
  for (int nt = 0; nt < 4; ++nt) {
    int px = nt * 16 + m;
    int gx = x0 + px;
    short4v v4;
#pragma unroll
    for (int r = 0; r < 4; ++r) {
      int co_r = co0 + r;
      size_t idx = ((size_t)(b * 64 + co_r) << 16) + (y << 8) + gx;
      float ov = xv[nt][r] + bias4[r] + acc[nt][r];
      out[idx] = ov;
      v4[r] = f2bs(ov);
    }
    int t2i = px * 64 + (((co0 >> 3) ^ (px & 7)) << 3) + (co0 & 7);
    *(short4v*)&tile[t2i] = v4;
  }
  __syncthreads();

  // ffn1: h1 = gelu(w1 . out + b1) for these 64 px -> q planes (0..63)
  short8 af1[2];
#pragma unroll
  for (int s = 0; s < 2; ++s) {
    short8 af;
#pragma unroll
    for (int j = 0; j < 8; ++j) af[j] = f2bs(w1[co * 64 + s * 32 + quad * 8 + j]);
    af1[s] = af;
  }
  floatx4 acc1[4];
#pragma unroll
  for (int nt = 0; nt < 4; ++nt) acc1[nt] = (floatx4){0.f, 0.f, 0.f, 0.f};
#pragma unroll
  for (int s = 0; s < 2; ++s) {
    int ci0 = s * 32 + quad * 8;
#pragma unroll
    for (int nt = 0; nt < 4; ++nt) {
      int px = nt * 16 + m;
      int ci = ci0 ^ ((px & 7) << 3);
      short8 bfrag = *(const short8*)&tile[px * 64 + ci];
      acc1[nt] = __builtin_amdgcn_mfma_f32_16x16x32_bf16(af1[s], bfrag, acc1[nt], 0, 0, 0);
    }
  }
  bf16* qb = qkv + ((size_t)(b * 192) << 16);
#pragma unroll
  for (int r = 0; r < 4; ++r) {
    int co_r = co0 + r;
    float bias = b1[co_r];
    bf16* op = qb + ((size_t)co_r << 16) + (y << 8) + x0;
#pragma unroll
    for (int nt = 0; nt < 4; ++nt)
      op[nt * 16 + m] = f2b(gelu_f(acc1[nt][r] + bias));
  }
}

// FUSED depthwise 3x3 + GELU + ffn2 1x1 + residual. grid (512, 1, 2b).
__global__ __launch_bounds__(256) void k_dwffn2(const bf16* __restrict__ qkv,
                                                const float* __restrict__ dw_w,
                                                const float* __restrict__ dw_b,
                                                const float* __restrict__ w2,
                                                const float* __restrict__ b2,
                                                float* __restrict__ out) {
  __shared__ __align__(16) bf16 tile[128 * 64];      // [px][ci], swizzled; 16 KB
  int tid = threadIdx.x;
  int bx = blockIdx.x, b = blockIdx.z;
  int y = bx >> 1, half = bx & 1;
  int x0 = half << 7;
  const bf16* qb = qkv + ((size_t)(b * 192) << 16);

  // ---- dw phase: 4 units/thread; unit = (ci, xseg of 8 px) ----
#pragma unroll 1
  for (int u = 0; u < 4; ++u) {
    int id = u * 256 + tid;                // [0, 1024)
    int ci = id >> 4, xseg = id & 15;
    int gx0 = x0 + (xseg << 3);
    const unsigned short* ip = (const unsigned short*)qb + ((size_t)ci << 16);

    float w[9];
#pragma unroll
    for (int p = 0; p < 9; ++p) w[p] = dw_w[ci * 9 + p];
    float bias = dw_b[ci];

    float kf[3][10];
#pragma unroll
    for (int rr = 0; rr < 3; ++rr) loadrow10(ip, y + rr - 1, gx0, kf[rr]);

#pragma unroll
    for (int i = 0; i < 8; ++i) {
      float acc = bias;
#pragma unroll
      for (int rr = 0; rr < 3; ++rr)
#pragma unroll
        for (int t = 0; t < 3; ++t)
          acc = fmaf(kf[rr][i + t], w[rr * 3 + t], acc);
      int px = (xseg << 3) + i;            // local px in [0,128)
      int addr = (px << 6) + ((((ci >> 3) ^ (px & 7)) << 3) | (ci & 7));
      tile[addr] = f2b(gelu_f(acc));
    }
  }
  __syncthreads();

  // ---- ffn2 GEMM from LDS + residual RMW ----
  int wv = tid >> 6, ln = tid & 63;
  int m = ln & 15, quad = ln >> 4;
  int co = wv * 16 + m;
  short8 afrag[2];
#pragma unroll
  for (int s = 0; s < 2; ++s) {
    short8 af;
#pragma unroll
    for (int j = 0; j < 8; ++j) af[j] = f2bs(w2[co * 64 + s * 32 + quad * 8 + j]);
    afrag[s] = af;
  }

  floatx4 acc[8];
#pragma unroll
  for (int nt = 0; nt < 8; ++nt) acc[nt] = (floatx4){0.f, 0.f, 0.f, 0.f};
#pragma unroll
  for (int s = 0; s < 2; ++s) {
    int ci0 = s * 32 + quad * 8;
#pragma unroll
    for (int nt = 0; nt < 8; ++nt) {
      int px = nt * 16 + m;
      int ci = ci0 ^ ((px & 7) << 3);
      short8 bfrag = *(const short8*)&tile[(px << 6) + ci];
      acc[nt] = __builtin_amdgcn_mfma_f32_16x16x32_bf16(afrag[s], bfrag, acc[nt], 0, 0, 0);
    }
  }

#pragma unroll
  for (int r = 0; r < 4; ++r) {
    int co_r = wv * 16 + quad * 4 + r;
    float bias = b2[co_r];
    float* op = out + ((size_t)b << 22) + ((size_t)co_r << 16) + (y << 8) + x0;
#pragma unroll
    for (int nt = 0; nt < 8; ++nt) {
      int i = nt * 16 + m;
      op[i] = op[i] + bias + acc[nt][r];
    }
  }
}

extern "C" void kernel_launch(void* const* d_in, const int* in_sizes, int n_in,
                              void* d_out, int out_size, void* d_ws, size_t ws_size,
                              hipStream_t stream) {
  const float* x      = (const float*)d_in[0];
  const float* qkv_w  = (const float*)d_in[1];
  const float* qkv_b  = (const float*)d_in[2];
  const float* proj_w = (const float*)d_in[3];
  const float* proj_b = (const float*)d_in[4];
  const float* ffn1_w = (const float*)d_in[5];
  const float* ffn1_b = (const float*)d_in[6];
  const float* dw_w   = (const float*)d_in[7];
  const float* dw_b   = (const float*)d_in[8];
  const float* ffn2_w = (const float*)d_in[9];
  const float* ffn2_b = (const float*)d_in[10];
  float* out = (float*)d_out;

  char* ws = (char*)d_ws;
  bf16*  qkvb  = (bf16*)ws;                    // 2 batch regions of [192, NPIX]
  float* kvb   = (float*)(ws + OFF_KV);
  float* ksb   = (float*)(ws + OFF_KS);
  bf16*  wpack = (bf16*)(ws + OFF_WP);

  // 6 launches total
  k_pack<<<144, 256, 0, stream>>>(proj_w, wpack, kvb);
  k_qkv_mfma<<<dim3(512, 2), 256, 0, stream>>>(x, qkv_w, qkv_b, qkvb);
  k_stats<<<dim3(32, 8, 16), 256, 0, stream>>>(qkvb, kvb, ksb);
  k_apply<<<dim3(64, 8, 2), 256, 0, stream>>>(qkvb, kvb, ksb);
  k_proj_ffn1<<<dim3(4, 256, 2), 256, 0, stream>>>(qkvb, wpack, proj_b, x,
                                                   ffn1_w, ffn1_b, out);
  k_dwffn2<<<dim3(512, 1, 2), 256, 0, stream>>>(qkvb, dw_w, dw_b,
                                                ffn2_w, ffn2_b, out);
}